// Round 19
// baseline (281.237 us; speedup 1.0000x reference)
//
#include <hip/hip_runtime.h>
#include <math.h>

#define BB 32
#define PP 32768
#define OO 50
#define NT 25            // truths per match block (2 halves)
#define NC 21

// histogram window: float exponents [104,136), 6 mantissa bits ->
// bin = (top16 - WBINLO) >> 1. Selection exact at any bin width; boundary-bin
// mean approx error ~2e-3 of output (tol 0.35).
#define WBINLO (104 << 7)
#define WBINS  2048

typedef unsigned long long u64;
typedef unsigned int u32;

static constexpr u32 HALF_BITS = 0x3F000000u;   // __float_as_uint(0.5f)

// u32 per-prior key: (iou_bits & ~63) | (49-o). The >=0.5 test stays EXACT
// under low-6-mantissa masking; max over halves picks smaller o on masked
// ties; sub-mask cross-half flips perturb one prior's term ~1e-3 (tol 0.35).
static constexpr size_t OFF_WHC   = 0;                            // u32[BB*WBINS] 256 KB
static constexpr size_t OFF_WHS   = OFF_WHC  + 4ull*BB*WBINS;     // f32[BB*WBINS] 256 KB
static constexpr size_t OFF_NPOS  = OFF_WHS  + 4ull*BB*WBINS;     // int[BB]
static constexpr size_t OFF_DACC  = OFF_NPOS + 128;               // double[3*BB]
static constexpr size_t OFF_DONEB = OFF_DACC + 8ull*3*BB;         // u32[BB] per-batch counters
static constexpr size_t OFF_DONE2 = OFF_DONEB + 128;              // u32 global counter
static constexpr size_t ZERO_BYTES = OFF_DONE2 + 16;              // 16-divisible
static constexpr size_t OFF_KPART = ((ZERO_BYTES + 127) & ~127ull); // u64[BB*OO*64] 820 KB
static constexpr size_t OFF_KEY2  = OFF_KPART + 8ull*BB*OO*64;    // u32[2*BB*PP] 8 MB

static __device__ __forceinline__ float fast_div(float a, float b) {
    return a * __builtin_amdgcn_rcpf(b);
}
static __device__ __forceinline__ u32 top16bits(float v) {
    u32 u = __float_as_uint(v);
    return (v > 0.0f) ? u : 0u;
}
static __device__ __forceinline__ u64 umax64(u64 a, u64 b) { return a > b ? a : b; }
static __device__ __forceinline__ u32 umax32(u32 a, u32 b) { return a > b ? a : b; }

// Per (chunk, b, half): 4 CONSECUTIVE priors per thread vs 25 truths.
// Per-prior best -> plain u32 key2 store; per-truth block winner -> plain
// kpart store (u64 key = iou_bits<<32 | 0xFFFFFFFF-p: max = smallest p).
__global__ __launch_bounds__(256) void match_kernel(
    const float* __restrict__ priors, const float* __restrict__ targets,
    u32* __restrict__ key2, u64* __restrict__ kpart, ulonglong2* __restrict__ zbase)
{
    const int b = blockIdx.y;
    const int half = blockIdx.z;
    const int obase = half * NT;
    const int tid = threadIdx.x;
    const int lane = tid & 63, wid = tid >> 6;
    const int chunk = blockIdx.x;
    const int p = chunk * 1024 + tid * 4;          // 4 consecutive priors

    // integrated zero of whc/whs/npos/dacc/doneb/done2
    if (b == 0 && half == 0) {
        for (size_t i = (size_t)chunk * 256 + tid; i < ZERO_BYTES / 16; i += 32 * 256)
            zbase[i] = make_ulonglong2(0ull, 0ull);
    }

    __shared__ float tr[NT * 5];
    __shared__ u64 wkeys[4][NT];
    if (tid < NT * 5) tr[tid] = targets[(size_t)b * OO * 5 + obase * 5 + tid];
    __syncthreads();

    float px1[4], py1[4], px2[4], py2[4], area_p[4];
#pragma unroll
    for (int s = 0; s < 4; ++s) {
        float4 pr = *(const float4*)(priors + (size_t)(p + s) * 4);
        px1[s] = pr.x - pr.z * 0.5f; py1[s] = pr.y - pr.w * 0.5f;
        px2[s] = pr.x + pr.z * 0.5f; py2[s] = pr.y + pr.w * 0.5f;
        area_p[s] = (px2[s] - px1[s]) * (py2[s] - py1[s]);
    }

    float bestv[4]; int besto[4];
#pragma unroll
    for (int s = 0; s < 4; ++s) { bestv[s] = -1.0f; besto[s] = 0; }

    for (int o = 0; o < NT; ++o) {
        float tx1 = tr[o*5+0], ty1 = tr[o*5+1], tx2 = tr[o*5+2], ty2 = tr[o*5+3];
        float area_t = (tx2 - tx1) * (ty2 - ty1);
        float iou[4];
#pragma unroll
        for (int s = 0; s < 4; ++s) {
            float ix1 = fmaxf(tx1, px1[s]), iy1 = fmaxf(ty1, py1[s]);
            float ix2 = fminf(tx2, px2[s]), iy2 = fminf(ty2, py2[s]);
            float dx = fmaxf(ix2 - ix1, 0.0f), dy = fmaxf(iy2 - iy1, 0.0f);
            float inter = dx * dy;
            iou[s] = fast_div(inter, (area_t + area_p[s]) - inter);
            if (iou[s] > bestv[s]) { bestv[s] = iou[s]; besto[s] = o; }
        }
        float tmax = iou[0]; int ts = 0;
#pragma unroll
        for (int s = 1; s < 4; ++s) if (iou[s] > tmax) { tmax = iou[s]; ts = s; }
        float mv = tmax;
        for (int m = 1; m < 64; m <<= 1)
            mv = fmaxf(mv, __shfl_xor(mv, m, 64));
        u64 bm = __ballot(tmax == mv);      // smallest lane = smallest p
        if (lane == (int)(__ffsll((long long)bm) - 1))
            wkeys[wid][o] = ((u64)__float_as_uint(mv) << 32)
                          | (u64)(0xFFFFFFFFu - (u32)(p + ts));
    }

    {
        uint4 kv;
        kv.x = (__float_as_uint(bestv[0]) & ~63u) | (u32)(49 - (obase + besto[0]));
        kv.y = (__float_as_uint(bestv[1]) & ~63u) | (u32)(49 - (obase + besto[1]));
        kv.z = (__float_as_uint(bestv[2]) & ~63u) | (u32)(49 - (obase + besto[2]));
        kv.w = (__float_as_uint(bestv[3]) & ~63u) | (u32)(49 - (obase + besto[3]));
        *(uint4*)(key2 + ((size_t)half * BB + b) * PP + p) = kv;
    }
    __syncthreads();
    if (tid < NT) {      // per-truth block winner, single writer per slot
        u64 k0 = wkeys[0][tid];
#pragma unroll
        for (int w = 1; w < 4; ++w) k0 = umax64(k0, wkeys[w][tid]);
        kpart[((size_t)b * OO + obase + tid) * 64 + chunk * 2 + half] = k0;
    }
}

// Register-resident score, 2 priors/thread; u32 keys merged in registers;
// forced table reduced from kpart; LDS count/value-sum hists. The LAST block
// per batch (doneb counter) runs the hard-negative selection inline; the
// last of those (done2) finalizes the outputs. 2 dispatches total.
#define EL2(k) ((((k) & 1) == 0) ? v[(k) >> 1].x : v[(k) >> 1].y)

__global__ __launch_bounds__(256) void score_kernel(
    const float* __restrict__ loc, const float* __restrict__ conf,
    const float* __restrict__ priors, const float* __restrict__ targets,
    const u32* __restrict__ key2, const u64* __restrict__ kpart,
    int* __restrict__ npos, double* __restrict__ dacc,
    u32* __restrict__ whc, float* __restrict__ whs,
    u32* __restrict__ doneb, u32* __restrict__ done2, float* __restrict__ out)
{
    const int b = blockIdx.y;
    const int tid = threadIdx.x;
    const int lane = tid & 63, wid = tid >> 6;
    const int p = blockIdx.x * 512 + tid * 2;        // 2 priors per thread
    __shared__ float tr[OO * 5];
    __shared__ u32 fp[OO];                           // forced prior per truth
    __shared__ __align__(16) u32 hh[WBINS];
    __shared__ __align__(16) float hs[WBINS];
    if (tid < OO * 5) tr[tid] = targets[(size_t)b * OO * 5 + tid];
    if (tid < OO) {                                  // reduce 64 chunk/half winners
        const u64* kp = kpart + ((size_t)b * OO + tid) * 64;
        u64 k0 = kp[0];
        for (int c = 1; c < 64; ++c) k0 = umax64(k0, kp[c]);
        fp[tid] = 0xFFFFFFFFu - (u32)(k0 & 0xFFFFFFFFull);
    }
#pragma unroll
    for (int j = 0; j < WBINS / 256; ++j) { hh[j * 256 + tid] = 0; hs[j * 256 + tid] = 0.0f; }
    __syncthreads();

    uint2 a01 = *(const uint2*)(key2 + (size_t)b * PP + p);
    uint2 c01 = *(const uint2*)(key2 + ((size_t)BB + b) * PP + p);
    const u32 kk[2] = {umax32(a01.x, c01.x), umax32(a01.y, c01.y)};

    int fo[2] = {-1, -1};
    for (int o = 0; o < OO; ++o) {
        u32 fpo = fp[o];
#pragma unroll
        for (int r = 0; r < 2; ++r) if (fpo == (u32)(p + r)) fo[r] = o;  // last wins
    }

    const float2* cp = (const float2*)(conf + (size_t)((size_t)b * PP + p) * NC);
    float2 v[21];
#pragma unroll
    for (int j = 0; j < 21; ++j) v[j] = cp[j];       // 42 floats = 2 rows

    float cev[2];
    double l_l = 0.0, pce = 0.0; int np_ = 0;

#pragma unroll
    for (int r = 0; r < 2; ++r) {
        const bool forced = fo[r] >= 0;
        const int o = forced ? fo[r] : (int)(49u - (kk[r] & 63u));
        const bool pos = forced || kk[r] >= HALF_BITS;   // exact (masking-safe)
        const int conft = pos ? (int)(tr[o * 5 + 4] + 1.0f) : 0;

        float m = -1e30f;
#pragma unroll
        for (int c = 0; c < NC; ++c) m = fmaxf(m, EL2(21 * r + c));
        float s = 0.0f, tl = 0.0f;
#pragma unroll
        for (int c = 0; c < NC; ++c) {
            float xx = EL2(21 * r + c);
            s += expf(xx - m);
            if (c == conft) tl = xx;
        }
        float ce = (m + logf(s)) - tl;
        cev[r] = pos ? 0.0f : ce;

        if (pos) {
            np_ += 1; pce += (double)ce;
            float mx1 = tr[o*5+0], my1 = tr[o*5+1], mx2 = tr[o*5+2], my2 = tr[o*5+3];
            float4 pr = *(const float4*)(priors + (size_t)(p + r) * 4);
            float lt0 = ((mx1 + mx2) * 0.5f - pr.x) / (0.1f * pr.z);
            float lt1 = ((my1 + my2) * 0.5f - pr.y) / (0.1f * pr.w);
            float lt2 = logf((mx2 - mx1) / pr.z) / 0.2f;
            float lt3 = logf((my2 - my1) / pr.w) / 0.2f;
            float4 l4 = *(const float4*)(loc + (size_t)((size_t)b * PP + p + r) * 4);
            float lpv[4] = {l4.x, l4.y, l4.z, l4.w};
            float lt[4] = {lt0, lt1, lt2, lt3};
#pragma unroll
            for (int i2 = 0; i2 < 4; ++i2) {
                float d = lpv[i2] - lt[i2];
                float ad = fabsf(d);
                l_l += (double)(ad < 1.0f ? 0.5f * d * d : ad - 0.5f);
            }
        }
    }

#pragma unroll
    for (int r = 0; r < 2; ++r) {
        u32 t16 = top16bits(cev[r]) >> 16;
        if (t16 != 0) {
            int widx = ((int)t16 - WBINLO) >> 1;
            widx = widx < 0 ? 0 : (widx > WBINS - 1 ? WBINS - 1 : widx);
            atomicAdd(&hh[widx], 1u);
            atomicAdd(&hs[widx], cev[r]);
        }
    }
    __syncthreads();
#pragma unroll
    for (int j = 0; j < WBINS / 256; ++j) {
        u32 c = hh[j * 256 + tid];
        if (c) {
            atomicAdd(&whc[(size_t)b * WBINS + j * 256 + tid], c);
            atomicAdd(&whs[(size_t)b * WBINS + j * 256 + tid], hs[j * 256 + tid]);
        }
    }
    __syncthreads();                      // flush reads done; alias reductions
    {
        double* rl = (double*)hh;
        double* rc = (double*)hs;
        int*    rn = (int*)(hh + 1024);
        rl[tid] = l_l; rc[tid] = pce; rn[tid] = np_;
        __syncthreads();
        for (int s2 = 128; s2 > 0; s2 >>= 1) {
            if (tid < s2) { rl[tid] += rl[tid+s2]; rc[tid] += rc[tid+s2]; rn[tid] += rn[tid+s2]; }
            __syncthreads();
        }
        if (tid == 0) {
            atomicAdd(&dacc[b], rl[0]);
            atomicAdd(&dacc[BB + b], rc[0]);
            atomicAdd(&npos[b], rn[0]);
        }
    }

    // ---- fused selection: last block per batch runs selwin inline ----
    __threadfence();
    __shared__ u32 s_rank;
    if (tid == 0) s_rank = atomicAdd(&doneb[b], 1u);
    __syncthreads();
    if (s_rank != 63u) return;
    __threadfence();                                  // acquire all b's flushes

    int k = npos[b] * 3; if (k > PP - 1) k = PP - 1;
    u32* ct = hh; float* fs = hs;                     // reuse LDS
    __shared__ u32 ccnt_[WBINS / 256]; __shared__ float csum_[WBINS / 256];
    __shared__ int s_cT; __shared__ u32 s_aboveC; __shared__ float s_aboveS;
    __shared__ u32 sT;

    if (k > 0) {
        const u32* hc = whc + (size_t)b * WBINS;
        const float* hsg = whs + (size_t)b * WBINS;
        for (int c = wid; c < WBINS / 256; c += 4) {
            u32 cnt = 0; float sm = 0.0f;
#pragma unroll
            for (int q = 0; q < 4; ++q) {
                int idx = c * 256 + q * 64 + lane;
                cnt += hc[idx];
                sm  += hsg[idx];
            }
            for (int m = 1; m < 64; m <<= 1) {
                cnt += __shfl_xor(cnt, m, 64);
                sm  += __shfl_xor(sm, m, 64);
            }
            if (lane == 0) { ccnt_[c] = cnt; csum_[c] = sm; }
        }
        if (tid == 0) sT = 0;
        __syncthreads();
        if (tid == 0) {
            u32 cum = 0; float scum = 0.0f; int cT = -1; u32 aC = 0; float aS = 0.0f;
            for (int c = WBINS / 256 - 1; c >= 0; --c) {
                if (cum + ccnt_[c] >= (u32)k) { cT = c; aC = cum; aS = scum; break; }
                cum += ccnt_[c]; scum += csum_[c];
            }
            s_cT = cT; s_aboveC = aC; s_aboveS = aS;
            if (cT < 0) dacc[2 * BB + b] = (double)scum;   // take all nonzero
        }
        __syncthreads();
        const int cT = s_cT;
        if (cT >= 0) {
            const u32 aboveC = s_aboveC; const float aboveS = s_aboveS;
            const u32 myc = (whc + (size_t)b * WBINS)[cT * 256 + tid];
            const float mys = (whs + (size_t)b * WBINS)[cT * 256 + tid];
            ct[tid] = myc; fs[tid] = mys;
            __syncthreads();
            for (int off = 1; off < 256; off <<= 1) {
                u32 a1 = (tid + off < 256) ? ct[tid + off] : 0;
                float a2 = (tid + off < 256) ? fs[tid + off] : 0.0f;
                __syncthreads();
                ct[tid] += a1; fs[tid] += a2;
                __syncthreads();
            }
            if (aboveC + ct[tid] >= (u32)k) atomicMax(&sT, (u32)tid);
            __syncthreads();
            const int T = (int)sT;
            if (tid == T) {
                u32 aboveBinC = aboveC + ((T < 255) ? ct[T + 1] : 0);
                float aboveBinS = aboveS + ((T < 255) ? fs[T + 1] : 0.0f);
                int k2 = k - (int)aboveBinC;
                double avg = (double)mys / (double)myc;    // boundary-bin mean
                dacc[2 * BB + b] = (double)aboveBinS + (double)k2 * avg;
            }
        }
    }
    __threadfence();                                  // publish dacc[2BB+b]
    __syncthreads();
    if (tid == 0) {
        u32 d = atomicAdd(done2, 1u);
        if (d == BB - 1) {                            // last batch finalizes
            __threadfence();
            double N = 0.0, ll = 0.0, lc = 0.0;
            for (int bb = 0; bb < BB; ++bb) {
                N += (double)npos[bb];
                ll += dacc[bb];
                lc += dacc[BB + bb] + dacc[2 * BB + bb];
            }
            out[0] = (float)(ll / N);
            out[1] = (float)(lc / N);
        }
    }
}

extern "C" void kernel_launch(void* const* d_in, const int* in_sizes, int n_in,
                              void* d_out, int out_size, void* d_ws, size_t ws_size,
                              hipStream_t stream) {
    const float* loc     = (const float*)d_in[0];
    const float* conf    = (const float*)d_in[1];
    const float* priors  = (const float*)d_in[2];
    const float* targets = (const float*)d_in[3];
    char* ws = (char*)d_ws;
    u32*    whc   = (u32*)   (ws + OFF_WHC);
    float*  whs   = (float*) (ws + OFF_WHS);
    int*    npos  = (int*)   (ws + OFF_NPOS);
    double* dacc  = (double*)(ws + OFF_DACC);
    u32*    doneb = (u32*)   (ws + OFF_DONEB);
    u32*    done2 = (u32*)   (ws + OFF_DONE2);
    u64*    kpart = (u64*)   (ws + OFF_KPART);
    u32*    key2  = (u32*)   (ws + OFF_KEY2);
    float*  out   = (float*)d_out;

    match_kernel<<<dim3(PP / 1024, BB, 2), 256, 0, stream>>>(priors, targets, key2, kpart, (ulonglong2*)ws);
    score_kernel<<<dim3(PP / 512, BB), 256, 0, stream>>>(loc, conf, priors, targets, key2, kpart,
                                                         npos, dacc, whc, whs, doneb, done2, out);
}

// Round 20
// 92.576 us; speedup vs baseline: 3.0379x; 3.0379x over previous
//
#include <hip/hip_runtime.h>
#include <math.h>

#define BB 32
#define PP 32768
#define OO 50
#define NT 25            // truths per match block (2 halves)
#define NC 21

// histogram window: float exponents [104,136), 6 mantissa bits ->
// bin = (top16 - WBINLO) >> 1. Selection exact at any bin width; boundary-bin
// mean approx error ~2e-3 of output (tol 0.35).
#define WBINLO (104 << 7)
#define WBINS  2048

typedef unsigned long long u64;
typedef unsigned int u32;

static constexpr u32 HALF_BITS = 0x3F000000u;   // __float_as_uint(0.5f)

// u32 per-prior key: (iou_bits & ~63) | (49-o). The >=0.5 test stays EXACT
// under low-6-mantissa masking (0.5 = 0x3F000000 has zero low bits); max over
// halves picks smaller o on masked ties (numpy first-max); sub-mask-width
// cross-half winner flips perturb one prior's loss term ~1e-3 (tol 0.35).
static constexpr size_t OFF_WHC   = 0;                            // u32[BB*WBINS] 256 KB
static constexpr size_t OFF_WHS   = OFF_WHC  + 4ull*BB*WBINS;     // f32[BB*WBINS] 256 KB
static constexpr size_t OFF_NPOS  = OFF_WHS  + 4ull*BB*WBINS;     // int[BB]
static constexpr size_t OFF_DACC  = OFF_NPOS + 128;               // double[3*BB]
static constexpr size_t OFF_DONE  = OFF_DACC + 8ull*3*BB;         // u32 done counter
static constexpr size_t ZERO_BYTES = OFF_DONE + 16;               // 16-divisible
static constexpr size_t OFF_KPART = ((ZERO_BYTES + 127) & ~127ull); // u64[BB*OO*64] 820 KB
static constexpr size_t OFF_KEY2  = OFF_KPART + 8ull*BB*OO*64;    // u32[2*BB*PP] 8 MB

static __device__ __forceinline__ float fast_div(float a, float b) {
    return a * __builtin_amdgcn_rcpf(b);
}
static __device__ __forceinline__ u32 top16bits(float v) {
    u32 u = __float_as_uint(v);
    return (v > 0.0f) ? u : 0u;
}
static __device__ __forceinline__ u64 umax64(u64 a, u64 b) { return a > b ? a : b; }
static __device__ __forceinline__ u32 umax32(u32 a, u32 b) { return a > b ? a : b; }

// Per (chunk, b, half): 4 CONSECUTIVE priors per thread vs 25 truths.
// Per-prior best -> plain u32 key2 store; per-truth block winner -> plain
// kpart store (u64 key = iou_bits<<32 | 0xFFFFFFFF-p: max = smallest p).
__global__ __launch_bounds__(256) void match_kernel(
    const float* __restrict__ priors, const float* __restrict__ targets,
    u32* __restrict__ key2, u64* __restrict__ kpart, ulonglong2* __restrict__ zbase)
{
    const int b = blockIdx.y;
    const int half = blockIdx.z;
    const int obase = half * NT;
    const int tid = threadIdx.x;
    const int lane = tid & 63, wid = tid >> 6;
    const int chunk = blockIdx.x;
    const int p = chunk * 1024 + tid * 4;          // 4 consecutive priors

    // integrated zero of whc/whs/npos/dacc/done (read only by later kernels)
    if (b == 0 && half == 0) {
        for (size_t i = (size_t)chunk * 256 + tid; i < ZERO_BYTES / 16; i += 32 * 256)
            zbase[i] = make_ulonglong2(0ull, 0ull);
    }

    __shared__ float tr[NT * 5];
    __shared__ u64 wkeys[4][NT];
    if (tid < NT * 5) tr[tid] = targets[(size_t)b * OO * 5 + obase * 5 + tid];
    __syncthreads();

    float px1[4], py1[4], px2[4], py2[4], area_p[4];
#pragma unroll
    for (int s = 0; s < 4; ++s) {
        float4 pr = *(const float4*)(priors + (size_t)(p + s) * 4);
        px1[s] = pr.x - pr.z * 0.5f; py1[s] = pr.y - pr.w * 0.5f;
        px2[s] = pr.x + pr.z * 0.5f; py2[s] = pr.y + pr.w * 0.5f;
        area_p[s] = (px2[s] - px1[s]) * (py2[s] - py1[s]);
    }

    float bestv[4]; int besto[4];
#pragma unroll
    for (int s = 0; s < 4; ++s) { bestv[s] = -1.0f; besto[s] = 0; }

    for (int o = 0; o < NT; ++o) {
        float tx1 = tr[o*5+0], ty1 = tr[o*5+1], tx2 = tr[o*5+2], ty2 = tr[o*5+3];
        float area_t = (tx2 - tx1) * (ty2 - ty1);
        float iou[4];
#pragma unroll
        for (int s = 0; s < 4; ++s) {
            float ix1 = fmaxf(tx1, px1[s]), iy1 = fmaxf(ty1, py1[s]);
            float ix2 = fminf(tx2, px2[s]), iy2 = fminf(ty2, py2[s]);
            float dx = fmaxf(ix2 - ix1, 0.0f), dy = fmaxf(iy2 - iy1, 0.0f);
            float inter = dx * dy;
            iou[s] = fast_div(inter, (area_t + area_p[s]) - inter);
            if (iou[s] > bestv[s]) { bestv[s] = iou[s]; besto[s] = o; }
        }
        // thread-local max, smallest-s tie (consecutive priors: s order = p order)
        float tmax = iou[0]; int ts = 0;
#pragma unroll
        for (int s = 1; s < 4; ++s) if (iou[s] > tmax) { tmax = iou[s]; ts = s; }
        float mv = tmax;
        for (int m = 1; m < 64; m <<= 1)
            mv = fmaxf(mv, __shfl_xor(mv, m, 64));
        u64 bm = __ballot(tmax == mv);      // smallest lane = smallest p
        if (lane == (int)(__ffsll((long long)bm) - 1))
            wkeys[wid][o] = ((u64)__float_as_uint(mv) << 32)
                          | (u64)(0xFFFFFFFFu - (u32)(p + ts));
    }

    // per-prior best for this half: u32 packed keys, plain coalesced store
    {
        uint4 kv;
        kv.x = (__float_as_uint(bestv[0]) & ~63u) | (u32)(49 - (obase + besto[0]));
        kv.y = (__float_as_uint(bestv[1]) & ~63u) | (u32)(49 - (obase + besto[1]));
        kv.z = (__float_as_uint(bestv[2]) & ~63u) | (u32)(49 - (obase + besto[2]));
        kv.w = (__float_as_uint(bestv[3]) & ~63u) | (u32)(49 - (obase + besto[3]));
        *(uint4*)(key2 + ((size_t)half * BB + b) * PP + p) = kv;
    }
    __syncthreads();
    if (tid < NT) {      // per-truth block winner, single writer per slot
        u64 k0 = wkeys[0][tid];
#pragma unroll
        for (int w = 1; w < 4; ++w) k0 = umax64(k0, wkeys[w][tid]);
        kpart[((size_t)b * OO + obase + tid) * 64 + chunk * 2 + half] = k0;
    }
}

// Register-resident score, 2 priors/thread; u32 keys merged in registers;
// forced table reduced from kpart; LDS count/value-sum hists.
#define EL2(k) ((((k) & 1) == 0) ? v[(k) >> 1].x : v[(k) >> 1].y)

__global__ __launch_bounds__(256) void score_kernel(
    const float* __restrict__ loc, const float* __restrict__ conf,
    const float* __restrict__ priors, const float* __restrict__ targets,
    const u32* __restrict__ key2, const u64* __restrict__ kpart,
    int* __restrict__ npos, double* __restrict__ dacc,
    u32* __restrict__ whc, float* __restrict__ whs)
{
    const int b = blockIdx.y;
    const int tid = threadIdx.x;
    const int p = blockIdx.x * 512 + tid * 2;        // 2 priors per thread
    __shared__ float tr[OO * 5];
    __shared__ u32 fp[OO];                           // forced prior per truth
    __shared__ __align__(16) u32 hh[WBINS];
    __shared__ __align__(16) float hs[WBINS];
    if (tid < OO * 5) tr[tid] = targets[(size_t)b * OO * 5 + tid];
    if (tid < OO) {                                  // reduce 64 chunk/half winners
        const u64* kp = kpart + ((size_t)b * OO + tid) * 64;
        u64 k0 = kp[0];
        for (int c = 1; c < 64; ++c) k0 = umax64(k0, kp[c]);
        fp[tid] = 0xFFFFFFFFu - (u32)(k0 & 0xFFFFFFFFull);
    }
#pragma unroll
    for (int j = 0; j < WBINS / 256; ++j) { hh[j * 256 + tid] = 0; hs[j * 256 + tid] = 0.0f; }
    __syncthreads();

    uint2 a01 = *(const uint2*)(key2 + (size_t)b * PP + p);
    uint2 c01 = *(const uint2*)(key2 + ((size_t)BB + b) * PP + p);
    const u32 kk[2] = {umax32(a01.x, c01.x), umax32(a01.y, c01.y)};

    int fo[2] = {-1, -1};
    for (int o = 0; o < OO; ++o) {
        u32 fpo = fp[o];
#pragma unroll
        for (int r = 0; r < 2; ++r) if (fpo == (u32)(p + r)) fo[r] = o;  // last wins
    }

    const float2* cp = (const float2*)(conf + (size_t)((size_t)b * PP + p) * NC);
    float2 v[21];
#pragma unroll
    for (int j = 0; j < 21; ++j) v[j] = cp[j];       // 42 floats = 2 rows

    float cev[2];
    double l_l = 0.0, pce = 0.0; int np_ = 0;

#pragma unroll
    for (int r = 0; r < 2; ++r) {
        const bool forced = fo[r] >= 0;
        const int o = forced ? fo[r] : (int)(49u - (kk[r] & 63u));
        const bool pos = forced || kk[r] >= HALF_BITS;   // exact (masking-safe)
        const int conft = pos ? (int)(tr[o * 5 + 4] + 1.0f) : 0;

        float m = -1e30f;
#pragma unroll
        for (int c = 0; c < NC; ++c) m = fmaxf(m, EL2(21 * r + c));
        float s = 0.0f, tl = 0.0f;
#pragma unroll
        for (int c = 0; c < NC; ++c) {
            float xx = EL2(21 * r + c);
            s += expf(xx - m);
            if (c == conft) tl = xx;
        }
        float ce = (m + logf(s)) - tl;
        cev[r] = pos ? 0.0f : ce;

        if (pos) {
            np_ += 1; pce += (double)ce;
            float mx1 = tr[o*5+0], my1 = tr[o*5+1], mx2 = tr[o*5+2], my2 = tr[o*5+3];
            float4 pr = *(const float4*)(priors + (size_t)(p + r) * 4);
            float lt0 = ((mx1 + mx2) * 0.5f - pr.x) / (0.1f * pr.z);
            float lt1 = ((my1 + my2) * 0.5f - pr.y) / (0.1f * pr.w);
            float lt2 = logf((mx2 - mx1) / pr.z) / 0.2f;
            float lt3 = logf((my2 - my1) / pr.w) / 0.2f;
            float4 l4 = *(const float4*)(loc + (size_t)((size_t)b * PP + p + r) * 4);
            float lpv[4] = {l4.x, l4.y, l4.z, l4.w};
            float lt[4] = {lt0, lt1, lt2, lt3};
#pragma unroll
            for (int i2 = 0; i2 < 4; ++i2) {
                float d = lpv[i2] - lt[i2];
                float ad = fabsf(d);
                l_l += (double)(ad < 1.0f ? 0.5f * d * d : ad - 0.5f);
            }
        }
    }

#pragma unroll
    for (int r = 0; r < 2; ++r) {
        u32 t16 = top16bits(cev[r]) >> 16;
        if (t16 != 0) {
            int widx = ((int)t16 - WBINLO) >> 1;
            widx = widx < 0 ? 0 : (widx > WBINS - 1 ? WBINS - 1 : widx);
            atomicAdd(&hh[widx], 1u);
            atomicAdd(&hs[widx], cev[r]);
        }
    }
    __syncthreads();
#pragma unroll
    for (int j = 0; j < WBINS / 256; ++j) {
        u32 c = hh[j * 256 + tid];
        if (c) {
            atomicAdd(&whc[(size_t)b * WBINS + j * 256 + tid], c);
            atomicAdd(&whs[(size_t)b * WBINS + j * 256 + tid], hs[j * 256 + tid]);
        }
    }
    __syncthreads();                      // flush reads done; alias reductions
    double* rl = (double*)hh;
    double* rc = (double*)hs;
    int*    rn = (int*)(hh + 1024);
    rl[tid] = l_l; rc[tid] = pce; rn[tid] = np_;
    __syncthreads();
    for (int s2 = 128; s2 > 0; s2 >>= 1) {
        if (tid < s2) { rl[tid] += rl[tid+s2]; rc[tid] += rc[tid+s2]; rn[tid] += rn[tid+s2]; }
        __syncthreads();
    }
    if (tid == 0) {
        atomicAdd(&dacc[b], rl[0]);
        atomicAdd(&dacc[BB + b], rc[0]);
        atomicAdd(&npos[b], rn[0]);
    }
}

// Select kernel (one block per batch) with FUSED finalize: last block to
// finish (device-scope done counter) reduces the 32 per-batch accumulators.
__global__ __launch_bounds__(256) void selwin_kernel(
    const u32* __restrict__ whc, const float* __restrict__ whs,
    const int* __restrict__ npos, double* __restrict__ dacc,
    u32* __restrict__ done, float* __restrict__ out)
{
    const int b = blockIdx.x, tid = threadIdx.x;
    const int lane = tid & 63, wid = tid >> 6;
    int k = npos[b] * 3; if (k > PP - 1) k = PP - 1;

    __shared__ u32 ccnt_[WBINS / 256]; __shared__ float csum_[WBINS / 256];
    __shared__ u32 ct[256]; __shared__ float fs[256];
    __shared__ int s_cT; __shared__ u32 s_aboveC; __shared__ float s_aboveS;
    __shared__ u32 sT;

    if (k > 0) {                                   // uniform branch per block
        const u32* hc = whc + (size_t)b * WBINS;
        const float* hsg = whs + (size_t)b * WBINS;
        for (int c = wid; c < WBINS / 256; c += 4) {
            u32 cnt = 0; float sm = 0.0f;
#pragma unroll
            for (int q = 0; q < 4; ++q) {
                int idx = c * 256 + q * 64 + lane;
                cnt += hc[idx];
                sm  += hsg[idx];
            }
            for (int m = 1; m < 64; m <<= 1) {
                cnt += __shfl_xor(cnt, m, 64);
                sm  += __shfl_xor(sm, m, 64);
            }
            if (lane == 0) { ccnt_[c] = cnt; csum_[c] = sm; }
        }
        if (tid == 0) sT = 0;
        __syncthreads();
        if (tid == 0) {
            u32 cum = 0; float scum = 0.0f; int cT = -1; u32 aC = 0; float aS = 0.0f;
            for (int c = WBINS / 256 - 1; c >= 0; --c) {
                if (cum + ccnt_[c] >= (u32)k) { cT = c; aC = cum; aS = scum; break; }
                cum += ccnt_[c]; scum += csum_[c];
            }
            s_cT = cT; s_aboveC = aC; s_aboveS = aS;
            if (cT < 0) { dacc[2 * BB + b] = (double)scum; __threadfence(); }
        }
        __syncthreads();
        const int cT = s_cT;
        if (cT >= 0) {                             // uniform branch per block
            const u32 aboveC = s_aboveC; const float aboveS = s_aboveS;
            const u32 myc = hc[cT * 256 + tid];
            const float mys = hsg[cT * 256 + tid];
            ct[tid] = myc; fs[tid] = mys;
            __syncthreads();
            for (int off = 1; off < 256; off <<= 1) {
                u32 a1 = (tid + off < 256) ? ct[tid + off] : 0;
                float a2 = (tid + off < 256) ? fs[tid + off] : 0.0f;
                __syncthreads();
                ct[tid] += a1; fs[tid] += a2;
                __syncthreads();
            }
            if (aboveC + ct[tid] >= (u32)k) atomicMax(&sT, (u32)tid);
            __syncthreads();
            const int T = (int)sT;
            if (tid == T) {
                u32 aboveBinC = aboveC + ((T < 255) ? ct[T + 1] : 0);
                float aboveBinS = aboveS + ((T < 255) ? fs[T + 1] : 0.0f);
                int k2 = k - (int)aboveBinC;
                double avg = (double)mys / (double)myc;    // boundary-bin mean
                dacc[2 * BB + b] = (double)aboveBinS + (double)k2 * avg;
                __threadfence();                            // publish before signal
            }
        }
    }
    __syncthreads();
    if (tid == 0) {
        u32 d = atomicAdd(done, 1u);                       // device-scope
        if (d == BB - 1) {                                 // last block finalizes
            __threadfence();
            double N = 0.0, ll = 0.0, lc = 0.0;
            for (int bb = 0; bb < BB; ++bb) {
                N += (double)npos[bb];
                ll += dacc[bb];
                lc += dacc[BB + bb] + dacc[2 * BB + bb];
            }
            out[0] = (float)(ll / N);
            out[1] = (float)(lc / N);
        }
    }
}

extern "C" void kernel_launch(void* const* d_in, const int* in_sizes, int n_in,
                              void* d_out, int out_size, void* d_ws, size_t ws_size,
                              hipStream_t stream) {
    const float* loc     = (const float*)d_in[0];
    const float* conf    = (const float*)d_in[1];
    const float* priors  = (const float*)d_in[2];
    const float* targets = (const float*)d_in[3];
    char* ws = (char*)d_ws;
    u32*    whc   = (u32*)   (ws + OFF_WHC);
    float*  whs   = (float*) (ws + OFF_WHS);
    int*    npos  = (int*)   (ws + OFF_NPOS);
    double* dacc  = (double*)(ws + OFF_DACC);
    u32*    done  = (u32*)   (ws + OFF_DONE);
    u64*    kpart = (u64*)   (ws + OFF_KPART);
    u32*    key2  = (u32*)   (ws + OFF_KEY2);
    float*  out   = (float*)d_out;

    match_kernel<<<dim3(PP / 1024, BB, 2), 256, 0, stream>>>(priors, targets, key2, kpart, (ulonglong2*)ws);
    score_kernel<<<dim3(PP / 512, BB), 256, 0, stream>>>(loc, conf, priors, targets, key2, kpart, npos, dacc, whc, whs);
    selwin_kernel<<<BB, 256, 0, stream>>>(whc, whs, npos, dacc, done, out);
}